// Round 7
// baseline (2081.298 us; speedup 1.0000x reference)
//
#include <hip/hip_runtime.h>
#include <cstdint>
#include <cstddef>

#define T_LEN 512
#define B_SZ  64
#define PH_T  64            // timesteps per phase
#define NPH   8
#define PHG_DW (2u*64u*PH_T*512u)   // G dwords per phase = 4,194,304

typedef _Float16 half2_t __attribute__((ext_vector_type(2)));

__device__ __forceinline__ float sigf(float x) { return 1.0f / (1.0f + __expf(-x)); }
__device__ __forceinline__ float tanhf_fast(float x) {
    x = fminf(fmaxf(x, -15.0f), 15.0f);
    float e = __expf(2.0f * x);
    return (e - 1.0f) / (e + 1.0f);
}

__device__ __forceinline__ float dot2u(unsigned a, unsigned b, float c) {
#if defined(__has_builtin) && __has_builtin(__builtin_amdgcn_fdot2)
    return __builtin_amdgcn_fdot2(__builtin_bit_cast(half2_t, a),
                                  __builtin_bit_cast(half2_t, b), c, false);
#else
    union U { unsigned u; _Float16 h[2]; } ua, ub;
    ua.u = a; ub.u = b;
    return c + (float)ua.h[0] * (float)ub.h[0] + (float)ua.h[1] * (float)ub.h[1];
#endif
}

__device__ __forceinline__ unsigned pkh(float x, float y) {
    union { _Float16 h[2]; unsigned u; } r;
    r.h[0] = (_Float16)x; r.h[1] = (_Float16)y;
    return r.u;
}
__device__ __forceinline__ float halfsel(unsigned g, int hi) {
    union { unsigned u; _Float16 h[2]; } r; r.u = g;
    return (float)r.h[hi];
}

// ---------------------------------------------------------------------------
// K_P: pack weights to f16-pair dwords.
//  o < 262144 : Whh, NEW recurrence layout:
//     o = ((((d*4+g)*16 + kpc)*512 + tid)*4 + j)
//     rr=tid>>1, kh=tid&1, row=256*g+rr, k0=kh*128+kpc*8+2j
//     -> a wave's uint4 load at fixed (d,g,kpc) is 1 KB coalesced.
//  o >= 262144: Wih, old gemm layout (m=2,3 as before).
// ---------------------------------------------------------------------------
__global__ void pack_w(const float* __restrict__ Whh_f, const float* __restrict__ Whh_b,
                       const float* __restrict__ Wih_f, const float* __restrict__ Wih_b,
                       unsigned* __restrict__ pk)
{
    int o = blockIdx.x * 256 + threadIdx.x;     // 0..524287
    if (o < 262144) {
        int j = o & 3, t = (o >> 2) & 511, kpc = (o >> 11) & 15;
        int g = (o >> 15) & 3, d = (o >> 17) & 1;
        int rr = t >> 1, kh = t & 1;
        int row = 256 * g + rr, k0 = kh * 128 + kpc * 8 + j * 2;
        const float* W = d ? Whh_b : Whh_f;
        pk[o] = pkh(W[(size_t)row * 256 + k0], W[(size_t)row * 256 + k0 + 1]);
    } else {
        int o2 = o - 262144;
        int j = o2 & 3, lane = (o2 >> 2) & 63, kpc = (o2 >> 8) & 31;
        int blk = (o2 >> 13) & 15, d = (o2 >> 17) & 1;
        int row = blk * 64 + lane, k0 = kpc * 8 + j * 2;
        const float* W = d ? Wih_b : Wih_f;
        pk[o] = pkh(W[(size_t)row * 256 + k0], W[(size_t)row * 256 + k0 + 1]);
    }
}

// ---------------------------------------------------------------------------
// Fused phase kernel. grid 768 x 512, static LDS 132 KB -> 1 block/CU.
//   blocks   0..127 : recurrence for phase lq  (1 chain (d,b) per block)
//   blocks 128..639 : input GEMM producing G[gq&1] for phase gq
//   blocks 640..767 : logit partials for phase logq (reads hout ring logq&1)
// Recurrence per thread: rr=tid>>1 (hidden idx), kh=tid&1 (k-half).
// Computes 4 gate rows over 128 k; gates are thread-local after one shfl_xor.
// ONE barrier per step. Weights: LDS-cached kpc 0..3 (128 KB), streamed
// kpc 4..15 (384 KB/step) with 3-deep ring prefetch. `zero` (host 0) blocks
// LICM from hoisting/rematerializing the streamed loads.
// ---------------------------------------------------------------------------
struct RecS {
    uint4    wl[4][4][512];    // [g][kpc0..3][tid]  = 128 KB
    unsigned hbuf[2][128];     // f16-pair h ping-pong
};
struct GemmS { unsigned x2[32][128]; };
struct LogS  { unsigned wout2[10][128]; };

__global__ __launch_bounds__(512) void fused_phase(
    const unsigned* __restrict__ pk, unsigned* __restrict__ G,
    const float* __restrict__ W_out, float* __restrict__ state,
    float* __restrict__ lh, unsigned* __restrict__ hout,
    const int* __restrict__ sent, const float* __restrict__ emb,
    const float* __restrict__ b_f, const float* __restrict__ b_b,
    int lq, int gq, int logq, int zero)
{
    __shared__ __align__(16) char smem[132096];
    const int tid = threadIdx.x;

    if (blockIdx.x < 128) {
        // ================= recurrence =================
        if (lq < 0) return;
        RecS& S = *(RecS*)smem;
        const int cid = blockIdx.x;          // d*64 + b
        const int d = cid >> 6;
        const int rr = tid >> 1, kh = tid & 1;
        const int hsel = rr & 1;

        // stage LDS-cached weights (kpc 0..3, all 4 gates)
#pragma unroll
        for (int g = 0; g < 4; ++g)
#pragma unroll
            for (int kc = 0; kc < 4; ++kc)
                S.wl[g][kc][tid] =
                    *(const uint4*)(pk + (((size_t)(d * 4 + g) * 16 + kc) * 2048) + tid * 4);

        float cc = state[((size_t)cid * 2 + 0) * 256 + rr];
        float hl = state[((size_t)cid * 2 + 1) * 256 + rr];
        {
            float hp2 = __shfl_xor(hl, 2, 64);
            if ((tid & 3) == 0) S.hbuf[0][tid >> 2] = pkh(hl, hp2);
        }
        __syncthreads();

        const unsigned* Gc = G + (size_t)(lq & 1) * PHG_DW + (size_t)cid * PH_T * 512;
        unsigned* Ho = hout + ((size_t)(lq & 1) * 128 + cid) * PH_T * 128;
        const unsigned* wsp = pk + (size_t)d * 4 * 16 * 2048 + tid * 4;

        for (int t = 0; t < PH_T; ++t) {
            const int cur = t & 1;
            // LICM-blocker: zero==0 always, but the compiler can't prove it
            const unsigned* wp_t = wsp + (size_t)(zero & t) * 2048;

            unsigned gx0 = Gc[t * 512 +   0 + (tid >> 2)];
            unsigned gx1 = Gc[t * 512 + 128 + (tid >> 2)];
            unsigned gx2 = Gc[t * 512 + 256 + (tid >> 2)];
            unsigned gx3 = Gc[t * 512 + 384 + (tid >> 2)];
            const unsigned* hb = &S.hbuf[cur][kh * 64];

            // ring prefetch: kpc 4..6 for all 4 gates
            uint4 sw[3][4];
#pragma unroll
            for (int pf = 0; pf < 3; ++pf)
#pragma unroll
                for (int g = 0; g < 4; ++g)
                    sw[pf][g] = *(const uint4*)(wp_t + ((size_t)g * 16 + 4 + pf) * 2048);

            float a0 = 0.f, a1 = 0.f, a2 = 0.f, a3 = 0.f;
            // cached kpc 0..3
#pragma unroll
            for (int kc = 0; kc < 4; ++kc) {
                uint4 hp = *(const uint4*)(hb + kc * 4);
                uint4 w;
                w = S.wl[0][kc][tid];
                a0 = dot2u(w.x, hp.x, a0); a0 = dot2u(w.y, hp.y, a0);
                a0 = dot2u(w.z, hp.z, a0); a0 = dot2u(w.w, hp.w, a0);
                w = S.wl[1][kc][tid];
                a1 = dot2u(w.x, hp.x, a1); a1 = dot2u(w.y, hp.y, a1);
                a1 = dot2u(w.z, hp.z, a1); a1 = dot2u(w.w, hp.w, a1);
                w = S.wl[2][kc][tid];
                a2 = dot2u(w.x, hp.x, a2); a2 = dot2u(w.y, hp.y, a2);
                a2 = dot2u(w.z, hp.z, a2); a2 = dot2u(w.w, hp.w, a2);
                w = S.wl[3][kc][tid];
                a3 = dot2u(w.x, hp.x, a3); a3 = dot2u(w.y, hp.y, a3);
                a3 = dot2u(w.z, hp.z, a3); a3 = dot2u(w.w, hp.w, a3);
            }
            // streamed kpc 4..15
#pragma unroll
            for (int kc = 4; kc < 16; ++kc) {
                uint4 hp = *(const uint4*)(hb + kc * 4);
                int slot = (kc - 4) % 3;
                uint4 w0 = sw[slot][0], w1 = sw[slot][1];
                uint4 w2 = sw[slot][2], w3 = sw[slot][3];
                if (kc + 3 < 16) {
#pragma unroll
                    for (int g = 0; g < 4; ++g)
                        sw[slot][g] = *(const uint4*)(wp_t + ((size_t)g * 16 + kc + 3) * 2048);
                }
                a0 = dot2u(w0.x, hp.x, a0); a0 = dot2u(w0.y, hp.y, a0);
                a0 = dot2u(w0.z, hp.z, a0); a0 = dot2u(w0.w, hp.w, a0);
                a1 = dot2u(w1.x, hp.x, a1); a1 = dot2u(w1.y, hp.y, a1);
                a1 = dot2u(w1.z, hp.z, a1); a1 = dot2u(w1.w, hp.w, a1);
                a2 = dot2u(w2.x, hp.x, a2); a2 = dot2u(w2.y, hp.y, a2);
                a2 = dot2u(w2.z, hp.z, a2); a2 = dot2u(w2.w, hp.w, a2);
                a3 = dot2u(w3.x, hp.x, a3); a3 = dot2u(w3.y, hp.y, a3);
                a3 = dot2u(w3.z, hp.z, a3); a3 = dot2u(w3.w, hp.w, a3);
            }
            // combine k-halves (kh pair); both threads end with identical sums
            a0 += __shfl_xor(a0, 1, 64);
            a1 += __shfl_xor(a1, 1, 64);
            a2 += __shfl_xor(a2, 1, 64);
            a3 += __shfl_xor(a3, 1, 64);

            float gi = a0 + halfsel(gx0, hsel);
            float gf = a1 + halfsel(gx1, hsel);
            float gg = a2 + halfsel(gx2, hsel);
            float go = a3 + halfsel(gx3, hsel);
            cc = sigf(gf) * cc + sigf(gi) * tanhf_fast(gg);
            float hn = sigf(go) * tanhf_fast(cc);
            hl = hn;
            float hp2 = __shfl_xor(hn, 2, 64);
            if ((tid & 3) == 0) {
                unsigned pair = pkh(hn, hp2);
                S.hbuf[cur ^ 1][tid >> 2] = pair;
                Ho[(size_t)t * 128 + (tid >> 2)] = pair;
            }
            __syncthreads();   // hbuf[nxt] visible; hbuf[cur] free for t+1 write
        }

        if (kh == 0) {
            state[((size_t)cid * 2 + 0) * 256 + rr] = cc;
            state[((size_t)cid * 2 + 1) * 256 + rr] = hl;
        }
    } else if (blockIdx.x < 640) {
        // ================= input GEMM for phase gq =================
        if (gq < 0) return;
        GemmS& S = *(GemmS*)smem;
        int gid = blockIdx.x - 128;                 // 0..511
        int d = gid & 1, rq = (gid >> 1) & 1, tt = (gid >> 2) & 1, b = gid >> 3;
        const float* bv = d ? b_b : b_f;

        int ti = tid >> 4, seg = tid & 15;
        int tg  = gq * PH_T + tt * 32 + ti;
        int tin = d ? (511 - tg) : tg;
        int tok = sent[b * 512 + tin];
        {
            const float4* ep = (const float4*)(emb + (size_t)tok * 256 + seg * 16);
            float4 e0 = ep[0], e1 = ep[1], e2 = ep[2], e3 = ep[3];
            unsigned* xp = &S.x2[ti][seg * 8];
            xp[0] = pkh(e0.x, e0.y); xp[1] = pkh(e0.z, e0.w);
            xp[2] = pkh(e1.x, e1.y); xp[3] = pkh(e1.z, e1.w);
            xp[4] = pkh(e2.x, e2.y); xp[5] = pkh(e2.z, e2.w);
            xp[6] = pkh(e3.x, e3.y); xp[7] = pkh(e3.z, e3.w);
        }
        __syncthreads();

        int row = rq * 512 + tid;
        int blk = row >> 6, lane = tid & 63;
        const unsigned* wp = pk + (((size_t)(2 + d) * 16 + blk) * 32) * 256 + lane * 4;

        float bias = bv[row];
        float acc[32];
#pragma unroll
        for (int t = 0; t < 32; ++t) acc[t] = bias;

        for (int kpc = 0; kpc < 32; ++kpc) {
            uint4 w = *(const uint4*)(wp + kpc * 256);
#pragma unroll
            for (int t = 0; t < 32; ++t) {
                uint4 xv = *(const uint4*)&S.x2[t][kpc * 4];
                acc[t] = dot2u(w.x, xv.x, acc[t]);
                acc[t] = dot2u(w.y, xv.y, acc[t]);
                acc[t] = dot2u(w.z, xv.z, acc[t]);
                acc[t] = dot2u(w.w, xv.w, acc[t]);
            }
        }

        unsigned* Gg = G + (size_t)(gq & 1) * PHG_DW;
        size_t gbase = ((size_t)(d * 64 + b) * PH_T + tt * 32) * 512;
#pragma unroll
        for (int t = 0; t < 32; ++t) {
            float part = __shfl_xor(acc[t], 1, 64);
            if (!(tid & 1))
                Gg[gbase + (size_t)t * 512 + (row >> 1)] = pkh(acc[t], part);
        }
    } else {
        // ================= logit partials for phase logq =================
        if (logq < 0) return;
        LogS& S = *(LogS*)smem;
        int cid = blockIdx.x - 640;                 // 0..127 = d*64+b
        int d = cid >> 6;

        for (int i = tid; i < 1280; i += 512) {
            int k = i >> 7, dw = i & 127;
            S.wout2[k][dw] = pkh(W_out[(size_t)k * 512 + d * 256 + 2 * dw],
                                 W_out[(size_t)k * 512 + d * 256 + 2 * dw + 1]);
        }
        __syncthreads();

        int tt = tid >> 3, seg = tid & 7;
        const unsigned* Hp = hout + ((size_t)(logq & 1) * 128 + cid) * PH_T * 128
                                  + (size_t)tt * 128 + seg * 16;
        float acc[10];
#pragma unroll
        for (int k = 0; k < 10; ++k) acc[k] = 0.f;
#pragma unroll
        for (int c4 = 0; c4 < 4; ++c4) {
            uint4 hv = *(const uint4*)(Hp + c4 * 4);
#pragma unroll
            for (int k = 0; k < 10; ++k) {
                const unsigned* wq = &S.wout2[k][seg * 16 + c4 * 4];
                acc[k] = dot2u(hv.x, wq[0], acc[k]);
                acc[k] = dot2u(hv.y, wq[1], acc[k]);
                acc[k] = dot2u(hv.z, wq[2], acc[k]);
                acc[k] = dot2u(hv.w, wq[3], acc[k]);
            }
        }
#pragma unroll
        for (int k = 0; k < 10; ++k) {
            acc[k] += __shfl_xor(acc[k], 1, 64);
            acc[k] += __shfl_xor(acc[k], 2, 64);
            acc[k] += __shfl_xor(acc[k], 4, 64);
        }
        if (seg == 0) {
            int tg = logq * PH_T + tt;
            int t_in = d ? (511 - tg) : tg;
#pragma unroll
            for (int k = 0; k < 10; ++k)
                lh[((size_t)cid * 512 + t_in) * 10 + k] = acc[k];
        }
    }
}

// ---------------------------------------------------------------------------
// K_V: Viterbi per batch element (proven structure).
// ---------------------------------------------------------------------------
__global__ __launch_bounds__(64) void viterbi_kernel(
    const float* __restrict__ lh, const float* __restrict__ b_out,
    const float* __restrict__ trans, float* __restrict__ out)
{
    int b = blockIdx.x;
    int l = threadIdx.x;
    __shared__ __align__(16) float ll[512][10];
    __shared__ int   bp[512][10];
    __shared__ float path[512];
    __shared__ float bo[10];
    if (l < 10) bo[l] = b_out[l];
    __syncthreads();

    const float* l0 = lh + (size_t)b * 5120;
    const float* l1 = lh + (size_t)(64 + b) * 5120;
    for (int i = l; i < 5120; i += 64) {
        int j = i - (i / 10) * 10;
        ((float*)ll)[i] = l0[i] + l1[i] + bo[j];
    }

    int j = (l < 10) ? l : 9;
    float tr[10];
#pragma unroll
    for (int i = 0; i < 10; ++i) tr[i] = trans[i * 10 + j];
    __syncthreads();

    float trellis = ll[0][j];
    for (int t = 1; t < 512; ++t) {
        float best = -3.0e30f; int arg = 0;
#pragma unroll
        for (int i = 0; i < 10; ++i) {
            float ti = __shfl(trellis, i, 64);
            float cand = ti + tr[i];
            bool gt = cand > best;
            best = gt ? cand : best;
            arg  = gt ? i : arg;
        }
        if (l < 10) bp[t][l] = arg;
        trellis = ll[t][j] + best;
    }

    float best = -3.0e30f; int arg = 0;
#pragma unroll
    for (int i = 0; i < 10; ++i) {
        float ti = __shfl(trellis, i, 64);
        bool gt = ti > best;
        best = gt ? ti : best;
        arg  = gt ? i : arg;
    }
    __syncthreads();
    if (l == 0) {
        out[b] = best;
        int tag = arg;
        path[511] = (float)tag;
        for (int t2 = 510; t2 >= 0; --t2) {
            tag = bp[t2 + 1][tag];
            path[t2] = (float)tag;
        }
    }
    __syncthreads();
    float* po = out + 64 + (size_t)b * 512;
    for (int i = l; i < 512; i += 64) po[i] = path[i];
}

// ---------------------------------------------------------------------------
extern "C" void kernel_launch(void* const* d_in, const int* in_sizes, int n_in,
                              void* d_out, int out_size, void* d_ws, size_t ws_size,
                              hipStream_t stream)
{
    (void)in_sizes; (void)n_in; (void)out_size; (void)ws_size;
    const int*   sent  = (const int*)d_in[0];
    const float* emb   = (const float*)d_in[2];
    const float* Wih_f = (const float*)d_in[3];
    const float* Whh_f = (const float*)d_in[4];
    const float* b_f   = (const float*)d_in[5];
    const float* Wih_b = (const float*)d_in[6];
    const float* Whh_b = (const float*)d_in[7];
    const float* b_b   = (const float*)d_in[8];
    const float* W_out = (const float*)d_in[9];
    const float* b_out = (const float*)d_in[10];
    const float* trans = (const float*)d_in[11];
    float* out = (float*)d_out;

    char* ws = (char*)d_ws;
    unsigned* pk    = (unsigned*)ws;                               // 2 MB
    unsigned* G     = (unsigned*)(ws + (2u << 20));                // 2 x 16.78 MB
    float*    lh    = (float*)(ws + 2097152u + 33554432u);         // 2.62 MB
    unsigned* hout  = (unsigned*)(ws + 2097152u + 33554432u + 2621440u);  // 8.39 MB
    float*    state = (float*)(ws + 2097152u + 33554432u + 2621440u + 8388608u); // 256 KB

    hipMemsetAsync(state, 0, (size_t)2 * 64 * 2 * 256 * 4, stream);

    hipLaunchKernelGGL(pack_w, dim3(2048), dim3(256), 0, stream,
                       Whh_f, Whh_b, Wih_f, Wih_b, pk);

    // pipeline: launch builds G(q+1) and logit-partials(q-1) while running phase q
    hipLaunchKernelGGL(fused_phase, dim3(768), dim3(512), 0, stream,
                       pk, G, W_out, state, lh, hout, sent, emb, b_f, b_b,
                       -1, 0, -1, 0);
    for (int q = 0; q < NPH; ++q) {
        hipLaunchKernelGGL(fused_phase, dim3(768), dim3(512), 0, stream,
                           pk, G, W_out, state, lh, hout, sent, emb, b_f, b_b,
                           q, (q < NPH - 1) ? (q + 1) : -1, q - 1, 0);
    }
    hipLaunchKernelGGL(fused_phase, dim3(768), dim3(512), 0, stream,
                       pk, G, W_out, state, lh, hout, sent, emb, b_f, b_b,
                       -1, -1, NPH - 1, 0);

    hipLaunchKernelGGL(viterbi_kernel, dim3(64), dim3(64), 0, stream,
                       lh, b_out, trans, out);
}

// Round 8
// 2019.146 us; speedup vs baseline: 1.0308x; 1.0308x over previous
//
#include <hip/hip_runtime.h>
#include <cstdint>
#include <cstddef>

#define T_LEN 512
#define B_SZ  64
#define PH_T  64            // timesteps per phase
#define NPH   8
#define PHG_DW (2u*64u*PH_T*512u)   // G dwords per phase = 4,194,304

typedef _Float16 half2_t __attribute__((ext_vector_type(2)));

__device__ __forceinline__ float sigf(float x) { return 1.0f / (1.0f + expf(-x)); }

__device__ __forceinline__ float dot2u(unsigned a, unsigned b, float c) {
#if defined(__has_builtin) && __has_builtin(__builtin_amdgcn_fdot2)
    return __builtin_amdgcn_fdot2(__builtin_bit_cast(half2_t, a),
                                  __builtin_bit_cast(half2_t, b), c, false);
#else
    union U { unsigned u; _Float16 h[2]; } ua, ub;
    ua.u = a; ub.u = b;
    return c + (float)ua.h[0] * (float)ub.h[0] + (float)ua.h[1] * (float)ub.h[1];
#endif
}

__device__ __forceinline__ unsigned pkh(float x, float y) {
    union { _Float16 h[2]; unsigned u; } r;
    r.h[0] = (_Float16)x; r.h[1] = (_Float16)y;
    return r.u;
}
__device__ __forceinline__ float halfsel(unsigned g, int hi) {
    union { unsigned u; _Float16 h[2]; } r; r.u = g;
    return (float)r.h[hi];
}

// ---------------------------------------------------------------------------
// K_P: pack all four weight matrices (f32 [1024][256]) into f16-pair dwords,
// lane-interleaved: idx = (((m*16+blk)*32 + kpc)*64 + lane)*4 + j
//   m: 0=Whh_f 1=Whh_b 2=Wih_f 3=Wih_b ; row = blk*64+lane ; k = kpc*8 + 2j(+1)
// ---------------------------------------------------------------------------
__global__ void pack_w(const float* __restrict__ Whh_f, const float* __restrict__ Whh_b,
                       const float* __restrict__ Wih_f, const float* __restrict__ Wih_b,
                       unsigned* __restrict__ pk)
{
    int o = blockIdx.x * 256 + threadIdx.x;     // 0..524287
    int j = o & 3, lane = (o >> 2) & 63, kpc = (o >> 8) & 31;
    int blk = (o >> 13) & 15, m = o >> 17;
    const float* W = (m == 0) ? Whh_f : (m == 1) ? Whh_b : (m == 2) ? Wih_f : Wih_b;
    int row = blk * 64 + lane, k0 = kpc * 8 + j * 2;
    pk[o] = pkh(W[(size_t)row * 256 + k0], W[(size_t)row * 256 + k0 + 1]);
}

// ---------------------------------------------------------------------------
// Fused phase kernel (R6 structure). grid 640 x 512, static LDS ~143 KB.
//   blocks 0..127   : recurrence for phase lq (1 chain (d,b) per block)
//   blocks 128..639 : input GEMM producing G[gq&1] for phase gq
// Recurrence weight residency per step (512 KB f16 Whh per direction):
//   kpc  0..15 : VGPR-resident -- loads PINNED via empty asm so the compiler
//                cannot rematerialize them inside the t-loop (R6's silent
//                failure: VGPR_Count=124 proved wr0/wr1 were re-streamed)
//   kpc 16..23 : LDS-resident (128 KB, staged once per phase)
//   kpc 24..31 : streamed from L2 (128 KB/step)
// ---------------------------------------------------------------------------
struct LstmS {
    uint4    wl[2][8][512];    // LDS-cached weight chunks (128 KB)
    unsigned hbuf[2][128];     // f16-pair h, ping-pong
    float    gsh[1024];        // gate pre-activations
    float    wout[10][256];    // W_out half for this direction
    float    lred[4][16];      // per-wave logit partials
};
struct GemmS {
    unsigned x2[32][128];      // f16-pair x tile [t][k-pair]
};

__global__ __launch_bounds__(512, 2) void fused_phase(
    const unsigned* __restrict__ pk, unsigned* __restrict__ G,
    const float* __restrict__ W_out, float* __restrict__ state,
    float* __restrict__ lh,
    const int* __restrict__ sent, const float* __restrict__ emb,
    const float* __restrict__ b_f, const float* __restrict__ b_b,
    int lq, int gq)
{
    __shared__ __align__(16) char smem[147456];
    const int tid = threadIdx.x;

    if (blockIdx.x < 128) {
        // ================= recurrence =================
        if (lq < 0) return;
        LstmS& S = *(LstmS*)smem;
        const int cid = blockIdx.x;
        const int d = cid & 1, b = cid >> 1;
        const int lane = tid & 63;

        for (int i = tid; i < 2560; i += 512) {
            int k = i >> 8, ih = i & 255;
            S.wout[k][ih] = W_out[(size_t)k * 512 + d * 256 + ih];
        }

        float cc = 0.f, hn = 0.f;
        if (tid < 256) {
            cc = state[((size_t)cid * 2 + 0) * 256 + tid];
            float hh = state[((size_t)cid * 2 + 1) * 256 + tid];
            float hp = __shfl_xor(hh, 1, 64);
            if (!(tid & 1)) S.hbuf[0][tid >> 1] = pkh(hh, hp);
        }

        const unsigned* w0p = pk + (((size_t)d * 16 +     (tid >> 6)) * 32) * 256 + lane * 4;
        const unsigned* w1p = pk + (((size_t)d * 16 + 8 + (tid >> 6)) * 32) * 256 + lane * 4;
        const unsigned* Gc  = G + (size_t)(lq & 1) * PHG_DW
                                + ((size_t)(d * 64 + b)) * PH_T * 512;
        const int hi = tid & 1;

        // ---- VGPR-resident weights: kpc 0..15 (128 VGPRs), loaded once ----
        uint4 wr0[16], wr1[16];
#pragma unroll
        for (int k = 0; k < 16; ++k) {
            wr0[k] = *(const uint4*)(w0p + k * 256);
            wr1[k] = *(const uint4*)(w1p + k * 256);
        }
        // PIN: opaque read-write asm -- values can no longer be remat'ed from
        // memory, forcing true register residency across the t-loop.
#pragma unroll
        for (int k = 0; k < 16; ++k) {
            asm volatile("" : "+v"(wr0[k].x), "+v"(wr0[k].y),
                              "+v"(wr0[k].z), "+v"(wr0[k].w),
                              "+v"(wr1[k].x), "+v"(wr1[k].y),
                              "+v"(wr1[k].z), "+v"(wr1[k].w));
        }
        // ---- LDS-resident weights: kpc 16..23 (128 KB) ----
#pragma unroll
        for (int k = 0; k < 8; ++k) {
            S.wl[0][k][tid] = *(const uint4*)(w0p + (16 + k) * 256);
            S.wl[1][k][tid] = *(const uint4*)(w1p + (16 + k) * 256);
        }
        __syncthreads();

        for (int t = 0; t < PH_T; ++t) {
            const int cur = t & 1;
            // ---- streamed weights: kpc 24..31, issued first ----
            uint4 s0[8], s1[8];
#pragma unroll
            for (int k = 0; k < 8; ++k) {
                s0[k] = *(const uint4*)(w0p + (24 + k) * 256);
                s1[k] = *(const uint4*)(w1p + (24 + k) * 256);
            }
            unsigned g0 = Gc[(size_t)t * 512 +       (tid >> 1)];
            unsigned g1 = Gc[(size_t)t * 512 + 256 + (tid >> 1)];
            const unsigned* hc = S.hbuf[cur];

            float a0 = 0.f, a1 = 0.f;
            // VGPR-cached chunks
#pragma unroll
            for (int k = 0; k < 16; ++k) {
                uint4 hp = *(const uint4*)&hc[k * 4];
                a0 = dot2u(wr0[k].x, hp.x, a0); a0 = dot2u(wr0[k].y, hp.y, a0);
                a0 = dot2u(wr0[k].z, hp.z, a0); a0 = dot2u(wr0[k].w, hp.w, a0);
                a1 = dot2u(wr1[k].x, hp.x, a1); a1 = dot2u(wr1[k].y, hp.y, a1);
                a1 = dot2u(wr1[k].z, hp.z, a1); a1 = dot2u(wr1[k].w, hp.w, a1);
            }
            // LDS-cached chunks
#pragma unroll
            for (int k = 0; k < 8; ++k) {
                uint4 hp = *(const uint4*)&hc[(16 + k) * 4];
                uint4 w0 = S.wl[0][k][tid];
                uint4 w1 = S.wl[1][k][tid];
                a0 = dot2u(w0.x, hp.x, a0); a0 = dot2u(w0.y, hp.y, a0);
                a0 = dot2u(w0.z, hp.z, a0); a0 = dot2u(w0.w, hp.w, a0);
                a1 = dot2u(w1.x, hp.x, a1); a1 = dot2u(w1.y, hp.y, a1);
                a1 = dot2u(w1.z, hp.z, a1); a1 = dot2u(w1.w, hp.w, a1);
            }
            // streamed chunks (loads have had the whole step to land)
#pragma unroll
            for (int k = 0; k < 8; ++k) {
                uint4 hp = *(const uint4*)&hc[(24 + k) * 4];
                a0 = dot2u(s0[k].x, hp.x, a0); a0 = dot2u(s0[k].y, hp.y, a0);
                a0 = dot2u(s0[k].z, hp.z, a0); a0 = dot2u(s0[k].w, hp.w, a0);
                a1 = dot2u(s1[k].x, hp.x, a1); a1 = dot2u(s1[k].y, hp.y, a1);
                a1 = dot2u(s1[k].z, hp.z, a1); a1 = dot2u(s1[k].w, hp.w, a1);
            }
            a0 += halfsel(g0, hi);
            a1 += halfsel(g1, hi);
            S.gsh[tid]       = a0;
            S.gsh[tid + 512] = a1;
            __syncthreads();                 // (1) gates ready

            if (tid < 256) {
                float iv = S.gsh[tid],       fv = S.gsh[256 + tid];
                float gg = S.gsh[512 + tid], ov = S.gsh[768 + tid];
                cc = sigf(fv) * cc + sigf(iv) * tanhf(gg);
                hn = sigf(ov) * tanhf(cc);
                float hp = __shfl_xor(hn, 1, 64);
                if (!(tid & 1)) S.hbuf[cur ^ 1][tid >> 1] = pkh(hn, hp);
                // logit partials: reduce hn * wout[k][:] over this wave
                float keep = 0.f;
#pragma unroll
                for (int k = 0; k < 10; ++k) {
                    float v = hn * S.wout[k][tid];
                    v += __shfl_xor(v, 1, 64);  v += __shfl_xor(v, 2, 64);
                    v += __shfl_xor(v, 4, 64);  v += __shfl_xor(v, 8, 64);
                    v += __shfl_xor(v, 16, 64); v += __shfl_xor(v, 32, 64);
                    if (lane == k) keep = v;
                }
                if (lane < 10) S.lred[tid >> 6][lane] = keep;
            }
            __syncthreads();                 // (2) h(t+1) + lred ready

            if (tid < 10) {
                float sum = S.lred[0][tid] + S.lred[1][tid]
                          + S.lred[2][tid] + S.lred[3][tid];
                int tg = lq * PH_T + t;
                int t_in = d ? (511 - tg) : tg;
                lh[((size_t)(d * 64 + b) * 512 + t_in) * 10 + tid] = sum;
            }
        }

        if (tid < 256) {
            state[((size_t)cid * 2 + 0) * 256 + tid] = cc;
            state[((size_t)cid * 2 + 1) * 256 + tid] = hn;
        }
    } else {
        // ================= input GEMM for phase gq =================
        if (gq < 0) return;
        GemmS& S = *(GemmS*)smem;
        int gid = blockIdx.x - 128;                 // 0..511
        int d = gid & 1, rq = (gid >> 1) & 1, tt = (gid >> 2) & 1, b = gid >> 3;
        const float* bv = d ? b_b : b_f;

        // stage x tile (32 t x 256 k) as f16 pairs
        int ti = tid >> 4, seg = tid & 15;
        int tg  = gq * PH_T + tt * 32 + ti;
        int tin = d ? (511 - tg) : tg;
        int tok = sent[b * 512 + tin];
        {
            const float4* ep = (const float4*)(emb + (size_t)tok * 256 + seg * 16);
            float4 e0 = ep[0], e1 = ep[1], e2 = ep[2], e3 = ep[3];
            unsigned* xp = &S.x2[ti][seg * 8];
            xp[0] = pkh(e0.x, e0.y); xp[1] = pkh(e0.z, e0.w);
            xp[2] = pkh(e1.x, e1.y); xp[3] = pkh(e1.z, e1.w);
            xp[4] = pkh(e2.x, e2.y); xp[5] = pkh(e2.z, e2.w);
            xp[6] = pkh(e3.x, e3.y); xp[7] = pkh(e3.z, e3.w);
        }
        __syncthreads();

        int row = rq * 512 + tid;
        int blk = row >> 6, lane = tid & 63;
        const unsigned* wp = pk + (((size_t)(2 + d) * 16 + blk) * 32) * 256 + lane * 4;

        float bias = bv[row];
        float acc[32];
#pragma unroll
        for (int t = 0; t < 32; ++t) acc[t] = bias;

        for (int kpc = 0; kpc < 32; ++kpc) {
            uint4 w = *(const uint4*)(wp + kpc * 256);
#pragma unroll
            for (int t = 0; t < 32; ++t) {
                uint4 xv = *(const uint4*)&S.x2[t][kpc * 4];
                acc[t] = dot2u(w.x, xv.x, acc[t]);
                acc[t] = dot2u(w.y, xv.y, acc[t]);
                acc[t] = dot2u(w.z, xv.z, acc[t]);
                acc[t] = dot2u(w.w, xv.w, acc[t]);
            }
        }

        unsigned* Gg = G + (size_t)(gq & 1) * PHG_DW;
        size_t gbase = ((size_t)(d * 64 + b) * PH_T + tt * 32) * 512;
#pragma unroll
        for (int t = 0; t < 32; ++t) {
            float part = __shfl_xor(acc[t], 1, 64);
            if (!(tid & 1))
                Gg[gbase + (size_t)t * 512 + (row >> 1)] = pkh(acc[t], part);
        }
    }
}

// ---------------------------------------------------------------------------
// K_V: Viterbi per batch element (proven structure).
// ---------------------------------------------------------------------------
__global__ __launch_bounds__(64) void viterbi_kernel(
    const float* __restrict__ lh, const float* __restrict__ b_out,
    const float* __restrict__ trans, float* __restrict__ out)
{
    int b = blockIdx.x;
    int l = threadIdx.x;
    __shared__ __align__(16) float ll[512][10];
    __shared__ int   bp[512][10];
    __shared__ float path[512];
    __shared__ float bo[10];
    if (l < 10) bo[l] = b_out[l];
    __syncthreads();

    const float* l0 = lh + (size_t)b * 5120;
    const float* l1 = lh + (size_t)(64 + b) * 5120;
    for (int i = l; i < 5120; i += 64) {
        int j = i - (i / 10) * 10;
        ((float*)ll)[i] = l0[i] + l1[i] + bo[j];
    }

    int j = (l < 10) ? l : 9;
    float tr[10];
#pragma unroll
    for (int i = 0; i < 10; ++i) tr[i] = trans[i * 10 + j];
    __syncthreads();

    float trellis = ll[0][j];
    for (int t = 1; t < 512; ++t) {
        float best = -3.0e30f; int arg = 0;
#pragma unroll
        for (int i = 0; i < 10; ++i) {
            float ti = __shfl(trellis, i, 64);
            float cand = ti + tr[i];
            bool gt = cand > best;
            best = gt ? cand : best;
            arg  = gt ? i : arg;
        }
        if (l < 10) bp[t][l] = arg;
        trellis = ll[t][j] + best;
    }

    float best = -3.0e30f; int arg = 0;
#pragma unroll
    for (int i = 0; i < 10; ++i) {
        float ti = __shfl(trellis, i, 64);
        bool gt = ti > best;
        best = gt ? ti : best;
        arg  = gt ? i : arg;
    }
    __syncthreads();
    if (l == 0) {
        out[b] = best;
        int tag = arg;
        path[511] = (float)tag;
        for (int t2 = 510; t2 >= 0; --t2) {
            tag = bp[t2 + 1][tag];
            path[t2] = (float)tag;
        }
    }
    __syncthreads();
    float* po = out + 64 + (size_t)b * 512;
    for (int i = l; i < 512; i += 64) po[i] = path[i];
}

// ---------------------------------------------------------------------------
extern "C" void kernel_launch(void* const* d_in, const int* in_sizes, int n_in,
                              void* d_out, int out_size, void* d_ws, size_t ws_size,
                              hipStream_t stream)
{
    (void)in_sizes; (void)n_in; (void)out_size; (void)ws_size;
    const int*   sent  = (const int*)d_in[0];
    const float* emb   = (const float*)d_in[2];
    const float* Wih_f = (const float*)d_in[3];
    const float* Whh_f = (const float*)d_in[4];
    const float* b_f   = (const float*)d_in[5];
    const float* Wih_b = (const float*)d_in[6];
    const float* Whh_b = (const float*)d_in[7];
    const float* b_b   = (const float*)d_in[8];
    const float* W_out = (const float*)d_in[9];
    const float* b_out = (const float*)d_in[10];
    const float* trans = (const float*)d_in[11];
    float* out = (float*)d_out;

    char* ws = (char*)d_ws;
    unsigned* pk    = (unsigned*)ws;                              // 2 MB
    unsigned* G     = (unsigned*)(ws + 2097152u);                 // 2 x 16.78 MB
    float*    lh    = (float*)(ws + 2097152u + 33554432u);        // 2.62 MB
    float*    state = (float*)(ws + 2097152u + 33554432u + 2621440u);  // 256 KB

    hipMemsetAsync(state, 0, (size_t)2 * 64 * 2 * 256 * 4, stream);

    hipLaunchKernelGGL(pack_w, dim3(2048), dim3(256), 0, stream,
                       Whh_f, Whh_b, Wih_f, Wih_b, pk);

    // pipeline: launch i builds G(i) while running recurrence phase i-1
    hipLaunchKernelGGL(fused_phase, dim3(640), dim3(512), 0, stream,
                       pk, G, W_out, state, lh, sent, emb, b_f, b_b, -1, 0);
    for (int q = 0; q < NPH; ++q) {
        hipLaunchKernelGGL(fused_phase, dim3(640), dim3(512), 0, stream,
                           pk, G, W_out, state, lh, sent, emb, b_f, b_b,
                           q, (q < NPH - 1) ? (q + 1) : -1);
    }

    hipLaunchKernelGGL(viterbi_kernel, dim3(64), dim3(64), 0, stream,
                       lh, b_out, trans, out);
}

// Round 9
// 1545.953 us; speedup vs baseline: 1.3463x; 1.3061x over previous
//
#include <hip/hip_runtime.h>
#include <cstdint>
#include <cstddef>

#define T_LEN 512
#define B_SZ  64
#define PH_T  64            // timesteps per phase
#define NPH   8
#define PHG_DW (2u*64u*PH_T*512u)   // G dwords per phase = 4,194,304

typedef _Float16 half2_t __attribute__((ext_vector_type(2)));

__device__ __forceinline__ float sigf(float x) { return 1.0f / (1.0f + expf(-x)); }

__device__ __forceinline__ float dot2u(unsigned a, unsigned b, float c) {
#if defined(__has_builtin) && __has_builtin(__builtin_amdgcn_fdot2)
    return __builtin_amdgcn_fdot2(__builtin_bit_cast(half2_t, a),
                                  __builtin_bit_cast(half2_t, b), c, false);
#else
    union U { unsigned u; _Float16 h[2]; } ua, ub;
    ua.u = a; ub.u = b;
    return c + (float)ua.h[0] * (float)ub.h[0] + (float)ua.h[1] * (float)ub.h[1];
#endif
}

__device__ __forceinline__ int sdot4(unsigned a, unsigned b, int c) {
#if defined(__has_builtin) && __has_builtin(__builtin_amdgcn_sdot4)
    return __builtin_amdgcn_sdot4((int)a, (int)b, c, false);
#else
    int r = c;
#pragma unroll
    for (int i = 0; i < 4; ++i) {
        int av = (int)(signed char)((a >> (8 * i)) & 0xff);
        int bv = (int)(signed char)((b >> (8 * i)) & 0xff);
        r += av * bv;
    }
    return r;
#endif
}

__device__ __forceinline__ unsigned pkh(float x, float y) {
    union { _Float16 h[2]; unsigned u; } r;
    r.h[0] = (_Float16)x; r.h[1] = (_Float16)y;
    return r.u;
}
__device__ __forceinline__ float halfsel(unsigned g, int hi) {
    union { unsigned u; _Float16 h[2]; } r; r.u = g;
    return (float)r.h[hi];
}

// ---------------------------------------------------------------------------
// K_P: pack Wih (and Whh f16, unused but harmless) as before -- gemm path
// is unchanged from R6.
// ---------------------------------------------------------------------------
__global__ void pack_w(const float* __restrict__ Whh_f, const float* __restrict__ Whh_b,
                       const float* __restrict__ Wih_f, const float* __restrict__ Wih_b,
                       unsigned* __restrict__ pk)
{
    int o = blockIdx.x * 256 + threadIdx.x;     // 0..524287
    int j = o & 3, lane = (o >> 2) & 63, kpc = (o >> 8) & 31;
    int blk = (o >> 13) & 15, m = o >> 17;
    const float* W = (m == 0) ? Whh_f : (m == 1) ? Whh_b : (m == 2) ? Wih_f : Wih_b;
    int row = blk * 64 + lane, k0 = kpc * 8 + j * 2;
    pk[o] = pkh(W[(size_t)row * 256 + k0], W[(size_t)row * 256 + k0 + 1]);
}

// ---------------------------------------------------------------------------
// K_A: per-row absmax of Whh (2048 rows). One wave per row.
// ---------------------------------------------------------------------------
__global__ void whh_amax(const float* __restrict__ Whh_f, const float* __restrict__ Whh_b,
                         float* __restrict__ amax)
{
    int row = blockIdx.x * 4 + (threadIdx.x >> 6);   // 0..2047
    int lane = threadIdx.x & 63;
    const float* W = (row < 1024) ? Whh_f : Whh_b;
    int r = row & 1023;
    float4 v = *(const float4*)(W + (size_t)r * 256 + lane * 4);
    float m = fmaxf(fmaxf(fabsf(v.x), fabsf(v.y)), fmaxf(fabsf(v.z), fabsf(v.w)));
#pragma unroll
    for (int s = 1; s < 64; s <<= 1) m = fmaxf(m, __shfl_xor(m, s, 64));
    if (lane == 0) amax[row] = fmaxf(m, 1e-12f);
}

// ---------------------------------------------------------------------------
// K_Q: quantize Whh -> int8, layout mirrors the f16 stream layout:
//   o = ((((d*16+blk)*16 + kpc)*64 + lane)*4 + j) ; row=blk*64+lane,
//   dword j covers k = kpc*16 + 4j .. +3.  Also emits per-row dequant
//   multiplier mrow = amax/(127*127)  (h is quantized with scale 127).
// ---------------------------------------------------------------------------
__global__ void pack_whh8(const float* __restrict__ Whh_f, const float* __restrict__ Whh_b,
                          const float* __restrict__ amax,
                          unsigned* __restrict__ q8, float* __restrict__ mrow)
{
    int o = blockIdx.x * 256 + threadIdx.x;     // 0..131071
    int j = o & 3, lane = (o >> 2) & 63, kpc = (o >> 8) & 15;
    int blk = (o >> 12) & 15, d = (o >> 16) & 1;
    int row = blk * 64 + lane, k0 = kpc * 16 + j * 4;
    const float* W = d ? Whh_b : Whh_f;
    float am = amax[d * 1024 + row];
    float s = 127.0f / am;
    unsigned out = 0;
#pragma unroll
    for (int i = 0; i < 4; ++i) {
        int q = (int)rintf(W[(size_t)row * 256 + k0 + i] * s);
        out |= ((unsigned)(q & 0xff)) << (8 * i);
    }
    q8[o] = out;
    if (kpc == 0 && j == 0)
        mrow[d * 1024 + row] = am * (1.0f / (127.0f * 127.0f));
}

// ---------------------------------------------------------------------------
// Fused phase kernel (R6 structure, int8 recurrence weights).
//   blocks 0..127   : recurrence for phase lq (1 chain (d,b) per block)
//   blocks 128..639 : input GEMM (f16, unchanged) producing G for phase gq
// Recurrence weights: 256 KB int8 per direction. kpc 8..15 LDS-cached
// (128 KB, staged once/phase); kpc 0..7 streamed (128 KB/step). h carried
// int8 (scale 127) in LDS ping-pong; accum int32 exact; per-row dequant.
// ---------------------------------------------------------------------------
struct LstmS {
    uint4    wl[2][8][512];    // int8 weight chunks kpc 8..15 (128 KB)
    unsigned hbuf[2][64];      // int8 h, ping-pong
    float    gsh[1024];        // gate pre-activations
    float    wout[10][256];    // W_out half for this direction
    float    lred[4][16];      // per-wave logit partials
};
struct GemmS {
    unsigned x2[32][128];      // f16-pair x tile [t][k-pair]
};

__global__ __launch_bounds__(512, 2) void fused_phase(
    const unsigned* __restrict__ pk, const unsigned* __restrict__ q8,
    const float* __restrict__ mrow, unsigned* __restrict__ G,
    const float* __restrict__ W_out, float* __restrict__ state,
    float* __restrict__ lh,
    const int* __restrict__ sent, const float* __restrict__ emb,
    const float* __restrict__ b_f, const float* __restrict__ b_b,
    int lq, int gq)
{
    __shared__ __align__(16) char smem[147456];
    const int tid = threadIdx.x;

    if (blockIdx.x < 128) {
        // ================= recurrence =================
        if (lq < 0) return;
        LstmS& S = *(LstmS*)smem;
        const int cid = blockIdx.x;
        const int d = cid & 1, b = cid >> 1;
        const int lane = tid & 63;

        for (int i = tid; i < 2560; i += 512) {
            int k = i >> 8, ih = i & 255;
            S.wout[k][ih] = W_out[(size_t)k * 512 + d * 256 + ih];
        }

        float cc = 0.f, hn = 0.f;
        if (tid < 256) {
            cc = state[((size_t)cid * 2 + 0) * 256 + tid];
            float hh = state[((size_t)cid * 2 + 1) * 256 + tid];
            int q = (int)rintf(hh * 127.0f);
            unsigned v = ((unsigned)(q & 0xff)) << ((tid & 3) * 8);
            v |= __shfl_xor(v, 1, 64);
            v |= __shfl_xor(v, 2, 64);
            if ((tid & 3) == 0) S.hbuf[0][tid >> 2] = v;
        }

        // int8 weight base pointers: rows r0=tid (a0), r1=512+tid (a1)
        const unsigned* w0p = q8 + ((size_t)(d * 16 +     (tid >> 6)) * 16) * 256 + lane * 4;
        const unsigned* w1p = q8 + ((size_t)(d * 16 + 8 + (tid >> 6)) * 16) * 256 + lane * 4;
        const unsigned* Gc  = G + (size_t)(lq & 1) * PHG_DW
                                + ((size_t)(d * 64 + b)) * PH_T * 512;
        const int hi = tid & 1;
        const float m0 = mrow[(size_t)d * 1024 + tid];
        const float m1 = mrow[(size_t)d * 1024 + 512 + tid];

        // ---- LDS-resident weights: kpc 8..15 (128 KB) ----
#pragma unroll
        for (int k = 0; k < 8; ++k) {
            S.wl[0][k][tid] = *(const uint4*)(w0p + (8 + k) * 256);
            S.wl[1][k][tid] = *(const uint4*)(w1p + (8 + k) * 256);
        }
        __syncthreads();

        for (int t = 0; t < PH_T; ++t) {
            const int cur = t & 1;
            // ---- streamed weights: kpc 0..7, issued first ----
            uint4 s0[8], s1[8];
#pragma unroll
            for (int k = 0; k < 8; ++k) {
                s0[k] = *(const uint4*)(w0p + k * 256);
                s1[k] = *(const uint4*)(w1p + k * 256);
            }
            unsigned g0 = Gc[(size_t)t * 512 +       (tid >> 1)];
            unsigned g1 = Gc[(size_t)t * 512 + 256 + (tid >> 1)];
            const unsigned* hc = S.hbuf[cur];

            int i0 = 0, i1 = 0;
            // LDS-cached chunks (kpc 8..15)
#pragma unroll
            for (int k = 0; k < 8; ++k) {
                uint4 hp = *(const uint4*)&hc[(8 + k) * 4];
                uint4 w0 = S.wl[0][k][tid];
                uint4 w1 = S.wl[1][k][tid];
                i0 = sdot4(w0.x, hp.x, i0); i0 = sdot4(w0.y, hp.y, i0);
                i0 = sdot4(w0.z, hp.z, i0); i0 = sdot4(w0.w, hp.w, i0);
                i1 = sdot4(w1.x, hp.x, i1); i1 = sdot4(w1.y, hp.y, i1);
                i1 = sdot4(w1.z, hp.z, i1); i1 = sdot4(w1.w, hp.w, i1);
            }
            // streamed chunks (kpc 0..7) -- loads have had the LDS pass to land
#pragma unroll
            for (int k = 0; k < 8; ++k) {
                uint4 hp = *(const uint4*)&hc[k * 4];
                i0 = sdot4(s0[k].x, hp.x, i0); i0 = sdot4(s0[k].y, hp.y, i0);
                i0 = sdot4(s0[k].z, hp.z, i0); i0 = sdot4(s0[k].w, hp.w, i0);
                i1 = sdot4(s1[k].x, hp.x, i1); i1 = sdot4(s1[k].y, hp.y, i1);
                i1 = sdot4(s1[k].z, hp.z, i1); i1 = sdot4(s1[k].w, hp.w, i1);
            }
            float a0 = (float)i0 * m0 + halfsel(g0, hi);
            float a1 = (float)i1 * m1 + halfsel(g1, hi);
            S.gsh[tid]       = a0;
            S.gsh[tid + 512] = a1;
            __syncthreads();                 // (1) gates ready

            if (tid < 256) {
                float iv = S.gsh[tid],       fv = S.gsh[256 + tid];
                float gg = S.gsh[512 + tid], ov = S.gsh[768 + tid];
                cc = sigf(fv) * cc + sigf(iv) * tanhf(gg);
                hn = sigf(ov) * tanhf(cc);
                int q = (int)rintf(hn * 127.0f);
                unsigned v = ((unsigned)(q & 0xff)) << ((tid & 3) * 8);
                v |= __shfl_xor(v, 1, 64);
                v |= __shfl_xor(v, 2, 64);
                if ((tid & 3) == 0) S.hbuf[cur ^ 1][tid >> 2] = v;
                // logit partials: reduce hn * wout[k][:] over this wave
                float keep = 0.f;
#pragma unroll
                for (int k = 0; k < 10; ++k) {
                    float vv = hn * S.wout[k][tid];
                    vv += __shfl_xor(vv, 1, 64);  vv += __shfl_xor(vv, 2, 64);
                    vv += __shfl_xor(vv, 4, 64);  vv += __shfl_xor(vv, 8, 64);
                    vv += __shfl_xor(vv, 16, 64); vv += __shfl_xor(vv, 32, 64);
                    if (lane == k) keep = vv;
                }
                if (lane < 10) S.lred[tid >> 6][lane] = keep;
            }
            __syncthreads();                 // (2) h(t+1) + lred ready

            if (tid < 10) {
                float sum = S.lred[0][tid] + S.lred[1][tid]
                          + S.lred[2][tid] + S.lred[3][tid];
                int tg = lq * PH_T + t;
                int t_in = d ? (511 - tg) : tg;
                lh[((size_t)(d * 64 + b) * 512 + t_in) * 10 + tid] = sum;
            }
        }

        if (tid < 256) {
            state[((size_t)cid * 2 + 0) * 256 + tid] = cc;
            state[((size_t)cid * 2 + 1) * 256 + tid] = hn;
        }
    } else {
        // ================= input GEMM for phase gq (f16, unchanged) ========
        if (gq < 0) return;
        GemmS& S = *(GemmS*)smem;
        int gid = blockIdx.x - 128;                 // 0..511
        int d = gid & 1, rq = (gid >> 1) & 1, tt = (gid >> 2) & 1, b = gid >> 3;
        const float* bv = d ? b_b : b_f;

        int ti = tid >> 4, seg = tid & 15;
        int tg  = gq * PH_T + tt * 32 + ti;
        int tin = d ? (511 - tg) : tg;
        int tok = sent[b * 512 + tin];
        {
            const float4* ep = (const float4*)(emb + (size_t)tok * 256 + seg * 16);
            float4 e0 = ep[0], e1 = ep[1], e2 = ep[2], e3 = ep[3];
            unsigned* xp = &S.x2[ti][seg * 8];
            xp[0] = pkh(e0.x, e0.y); xp[1] = pkh(e0.z, e0.w);
            xp[2] = pkh(e1.x, e1.y); xp[3] = pkh(e1.z, e1.w);
            xp[4] = pkh(e2.x, e2.y); xp[5] = pkh(e2.z, e2.w);
            xp[6] = pkh(e3.x, e3.y); xp[7] = pkh(e3.z, e3.w);
        }
        __syncthreads();

        int row = rq * 512 + tid;
        int blk = row >> 6, lane = tid & 63;
        const unsigned* wp = pk + (((size_t)(2 + d) * 16 + blk) * 32) * 256 + lane * 4;

        float bias = bv[row];
        float acc[32];
#pragma unroll
        for (int t = 0; t < 32; ++t) acc[t] = bias;

        for (int kpc = 0; kpc < 32; ++kpc) {
            uint4 w = *(const uint4*)(wp + kpc * 256);
#pragma unroll
            for (int t = 0; t < 32; ++t) {
                uint4 xv = *(const uint4*)&S.x2[t][kpc * 4];
                acc[t] = dot2u(w.x, xv.x, acc[t]);
                acc[t] = dot2u(w.y, xv.y, acc[t]);
                acc[t] = dot2u(w.z, xv.z, acc[t]);
                acc[t] = dot2u(w.w, xv.w, acc[t]);
            }
        }

        unsigned* Gg = G + (size_t)(gq & 1) * PHG_DW;
        size_t gbase = ((size_t)(d * 64 + b) * PH_T + tt * 32) * 512;
#pragma unroll
        for (int t = 0; t < 32; ++t) {
            float part = __shfl_xor(acc[t], 1, 64);
            if (!(tid & 1))
                Gg[gbase + (size_t)t * 512 + (row >> 1)] = pkh(acc[t], part);
        }
    }
}

// ---------------------------------------------------------------------------
// K_V: Viterbi per batch element (proven structure).
// ---------------------------------------------------------------------------
__global__ __launch_bounds__(64) void viterbi_kernel(
    const float* __restrict__ lh, const float* __restrict__ b_out,
    const float* __restrict__ trans, float* __restrict__ out)
{
    int b = blockIdx.x;
    int l = threadIdx.x;
    __shared__ __align__(16) float ll[512][10];
    __shared__ int   bp[512][10];
    __shared__ float path[512];
    __shared__ float bo[10];
    if (l < 10) bo[l] = b_out[l];
    __syncthreads();

    const float* l0 = lh + (size_t)b * 5120;
    const float* l1 = lh + (size_t)(64 + b) * 5120;
    for (int i = l; i < 5120; i += 64) {
        int j = i - (i / 10) * 10;
        ((float*)ll)[i] = l0[i] + l1[i] + bo[j];
    }

    int j = (l < 10) ? l : 9;
    float tr[10];
#pragma unroll
    for (int i = 0; i < 10; ++i) tr[i] = trans[i * 10 + j];
    __syncthreads();

    float trellis = ll[0][j];
    for (int t = 1; t < 512; ++t) {
        float best = -3.0e30f; int arg = 0;
#pragma unroll
        for (int i = 0; i < 10; ++i) {
            float ti = __shfl(trellis, i, 64);
            float cand = ti + tr[i];
            bool gt = cand > best;
            best = gt ? cand : best;
            arg  = gt ? i : arg;
        }
        if (l < 10) bp[t][l] = arg;
        trellis = ll[t][j] + best;
    }

    float best = -3.0e30f; int arg = 0;
#pragma unroll
    for (int i = 0; i < 10; ++i) {
        float ti = __shfl(trellis, i, 64);
        bool gt = ti > best;
        best = gt ? ti : best;
        arg  = gt ? i : arg;
    }
    __syncthreads();
    if (l == 0) {
        out[b] = best;
        int tag = arg;
        path[511] = (float)tag;
        for (int t2 = 510; t2 >= 0; --t2) {
            tag = bp[t2 + 1][tag];
            path[t2] = (float)tag;
        }
    }
    __syncthreads();
    float* po = out + 64 + (size_t)b * 512;
    for (int i = l; i < 512; i += 64) po[i] = path[i];
}

// ---------------------------------------------------------------------------
extern "C" void kernel_launch(void* const* d_in, const int* in_sizes, int n_in,
                              void* d_out, int out_size, void* d_ws, size_t ws_size,
                              hipStream_t stream)
{
    (void)in_sizes; (void)n_in; (void)out_size; (void)ws_size;
    const int*   sent  = (const int*)d_in[0];
    const float* emb   = (const float*)d_in[2];
    const float* Wih_f = (const float*)d_in[3];
    const float* Whh_f = (const float*)d_in[4];
    const float* b_f   = (const float*)d_in[5];
    const float* Wih_b = (const float*)d_in[6];
    const float* Whh_b = (const float*)d_in[7];
    const float* b_b   = (const float*)d_in[8];
    const float* W_out = (const float*)d_in[9];
    const float* b_out = (const float*)d_in[10];
    const float* trans = (const float*)d_in[11];
    float* out = (float*)d_out;

    char* ws = (char*)d_ws;
    unsigned* pk    = (unsigned*)ws;                              // 2 MB
    unsigned* G     = (unsigned*)(ws + 2097152u);                 // 2 x 16.78 MB
    float*    lh    = (float*)(ws + 2097152u + 33554432u);        // 2.62 MB
    float*    state = (float*)(ws + 2097152u + 33554432u + 2621440u);  // 256 KB
    unsigned* q8    = (unsigned*)(ws + 2097152u + 33554432u + 2621440u + 262144u); // 512 KB
    float*    amax  = (float*)(ws + 2097152u + 33554432u + 2621440u + 262144u + 524288u); // 8 KB
    float*    mrowp = (float*)(ws + 2097152u + 33554432u + 2621440u + 262144u + 524288u + 8192u); // 8 KB

    hipMemsetAsync(state, 0, (size_t)2 * 64 * 2 * 256 * 4, stream);

    hipLaunchKernelGGL(pack_w, dim3(2048), dim3(256), 0, stream,
                       Whh_f, Whh_b, Wih_f, Wih_b, pk);
    hipLaunchKernelGGL(whh_amax, dim3(512), dim3(256), 0, stream,
                       Whh_f, Whh_b, amax);
    hipLaunchKernelGGL(pack_whh8, dim3(512), dim3(256), 0, stream,
                       Whh_f, Whh_b, amax, q8, mrowp);

    // pipeline: launch i builds G(i) while running recurrence phase i-1
    hipLaunchKernelGGL(fused_phase, dim3(640), dim3(512), 0, stream,
                       pk, q8, mrowp, G, W_out, state, lh, sent, emb, b_f, b_b, -1, 0);
    for (int q = 0; q < NPH; ++q) {
        hipLaunchKernelGGL(fused_phase, dim3(640), dim3(512), 0, stream,
                           pk, q8, mrowp, G, W_out, state, lh, sent, emb, b_f, b_b,
                           q, (q < NPH - 1) ? (q + 1) : -1);
    }

    hipLaunchKernelGGL(viterbi_kernel, dim3(64), dim3(64), 0, stream,
                       lh, b_out, trans, out);
}

// Round 10
// 1164.226 us; speedup vs baseline: 1.7877x; 1.3279x over previous
//
#include <hip/hip_runtime.h>
#include <cstdint>
#include <cstddef>

#define T_LEN 512
#define B_SZ  64
#define PH_T  64            // timesteps per phase
#define NPH   8
#define PHG_DW (2u*64u*PH_T*512u)   // G dwords per phase = 4,194,304

typedef _Float16 half2_t __attribute__((ext_vector_type(2)));

__device__ __forceinline__ float sigf(float x) { return 1.0f / (1.0f + expf(-x)); }

__device__ __forceinline__ float dot2u(unsigned a, unsigned b, float c) {
#if defined(__has_builtin) && __has_builtin(__builtin_amdgcn_fdot2)
    return __builtin_amdgcn_fdot2(__builtin_bit_cast(half2_t, a),
                                  __builtin_bit_cast(half2_t, b), c, false);
#else
    union U { unsigned u; _Float16 h[2]; } ua, ub;
    ua.u = a; ub.u = b;
    return c + (float)ua.h[0] * (float)ub.h[0] + (float)ua.h[1] * (float)ub.h[1];
#endif
}

__device__ __forceinline__ int sdot4(unsigned a, unsigned b, int c) {
#if defined(__has_builtin) && __has_builtin(__builtin_amdgcn_sdot4)
    return __builtin_amdgcn_sdot4((int)a, (int)b, c, false);
#else
    int r = c;
#pragma unroll
    for (int i = 0; i < 4; ++i) {
        int av = (int)(signed char)((a >> (8 * i)) & 0xff);
        int bv = (int)(signed char)((b >> (8 * i)) & 0xff);
        r += av * bv;
    }
    return r;
#endif
}

__device__ __forceinline__ unsigned pkh(float x, float y) {
    union { _Float16 h[2]; unsigned u; } r;
    r.h[0] = (_Float16)x; r.h[1] = (_Float16)y;
    return r.u;
}
__device__ __forceinline__ float halfsel(unsigned g, int hi) {
    union { unsigned u; _Float16 h[2]; } r; r.u = g;
    return (float)r.h[hi];
}

// ---------------------------------------------------------------------------
// K_P: pack Wih/Whh f16 (gemm path unchanged; Whh-f16 slots unused).
// ---------------------------------------------------------------------------
__global__ void pack_w(const float* __restrict__ Whh_f, const float* __restrict__ Whh_b,
                       const float* __restrict__ Wih_f, const float* __restrict__ Wih_b,
                       unsigned* __restrict__ pk)
{
    int o = blockIdx.x * 256 + threadIdx.x;     // 0..524287
    int j = o & 3, lane = (o >> 2) & 63, kpc = (o >> 8) & 31;
    int blk = (o >> 13) & 15, m = o >> 17;
    const float* W = (m == 0) ? Whh_f : (m == 1) ? Whh_b : (m == 2) ? Wih_f : Wih_b;
    int row = blk * 64 + lane, k0 = kpc * 8 + j * 2;
    pk[o] = pkh(W[(size_t)row * 256 + k0], W[(size_t)row * 256 + k0 + 1]);
}

// ---------------------------------------------------------------------------
// K_A: per-row absmax of Whh (2048 rows). One wave per row.
// ---------------------------------------------------------------------------
__global__ void whh_amax(const float* __restrict__ Whh_f, const float* __restrict__ Whh_b,
                         float* __restrict__ amax)
{
    int row = blockIdx.x * 4 + (threadIdx.x >> 6);   // 0..2047
    int lane = threadIdx.x & 63;
    const float* W = (row < 1024) ? Whh_f : Whh_b;
    int r = row & 1023;
    float4 v = *(const float4*)(W + (size_t)r * 256 + lane * 4);
    float m = fmaxf(fmaxf(fabsf(v.x), fabsf(v.y)), fmaxf(fabsf(v.z), fabsf(v.w)));
#pragma unroll
    for (int s = 1; s < 64; s <<= 1) m = fmaxf(m, __shfl_xor(m, s, 64));
    if (lane == 0) amax[row] = fmaxf(m, 1e-12f);
}

// ---------------------------------------------------------------------------
// K_Q: quantize Whh -> int8 (layout as R9); per-row dequant multiplier.
// ---------------------------------------------------------------------------
__global__ void pack_whh8(const float* __restrict__ Whh_f, const float* __restrict__ Whh_b,
                          const float* __restrict__ amax,
                          unsigned* __restrict__ q8, float* __restrict__ mrow)
{
    int o = blockIdx.x * 256 + threadIdx.x;     // 0..131071
    int j = o & 3, lane = (o >> 2) & 63, kpc = (o >> 8) & 15;
    int blk = (o >> 12) & 15, d = (o >> 16) & 1;
    int row = blk * 64 + lane, k0 = kpc * 16 + j * 4;
    const float* W = d ? Whh_b : Whh_f;
    float am = amax[d * 1024 + row];
    float s = 127.0f / am;
    unsigned out = 0;
#pragma unroll
    for (int i = 0; i < 4; ++i) {
        int q = (int)rintf(W[(size_t)row * 256 + k0 + i] * s);
        out |= ((unsigned)(q & 0xff)) << (8 * i);
    }
    q8[o] = out;
    if (kpc == 0 && j == 0)
        mrow[d * 1024 + row] = am * (1.0f / (127.0f * 127.0f));
}

// ---------------------------------------------------------------------------
// Fused phase kernel. grid 768 x 512, static LDS ~150 KB -> 1 block/CU.
//   blocks 0..127   : recurrence for phase lq (int8 weights, de-fused logits)
//   blocks 128..639 : input GEMM (f16) producing G for phase gq
//   blocks 640..767 : logit partials for phase logq (reads hout ring)
// Recurrence weights: kpc 7..15 LDS-cached (144 KB); kpc 0..6 streamed
// (112 KB/step). h int8 ping-pong; logits de-fused -> recurrence epilogue is
// just gate assembly + h pack + Ho store. gsh halved (upper threads write).
// ---------------------------------------------------------------------------
struct LstmS {
    uint4    wl[2][9][512];    // int8 weight chunks kpc 7..15 (144 KB)
    unsigned hbuf[2][64];      // int8 h, ping-pong
    float    gsh[512];         // f/o gate pre-activations (from upper threads)
};
struct GemmS { unsigned x2[32][128]; };
struct LogS  { unsigned wout2[10][128]; };

__global__ __launch_bounds__(512, 2) void fused_phase(
    const unsigned* __restrict__ pk, const unsigned* __restrict__ q8,
    const float* __restrict__ mrow, unsigned* __restrict__ G,
    const float* __restrict__ W_out, float* __restrict__ state,
    float* __restrict__ lh, unsigned* __restrict__ hout,
    const int* __restrict__ sent, const float* __restrict__ emb,
    const float* __restrict__ b_f, const float* __restrict__ b_b,
    int lq, int gq, int logq)
{
    __shared__ __align__(16) char smem[150016];
    const int tid = threadIdx.x;

    if (blockIdx.x < 128) {
        // ================= recurrence =================
        if (lq < 0) return;
        LstmS& S = *(LstmS*)smem;
        const int cid = blockIdx.x;
        const int d = cid & 1, b = cid >> 1;
        const int lane = tid & 63;

        float cc = 0.f, hn = 0.f;
        if (tid < 256) {
            cc = state[((size_t)cid * 2 + 0) * 256 + tid];
            float hh = state[((size_t)cid * 2 + 1) * 256 + tid];
            int q = (int)rintf(hh * 127.0f);
            unsigned v = ((unsigned)(q & 0xff)) << ((tid & 3) * 8);
            v |= __shfl_xor(v, 1, 64);
            v |= __shfl_xor(v, 2, 64);
            if ((tid & 3) == 0) S.hbuf[0][tid >> 2] = v;
        }

        const unsigned* w0p = q8 + ((size_t)(d * 16 +     (tid >> 6)) * 16) * 256 + lane * 4;
        const unsigned* w1p = q8 + ((size_t)(d * 16 + 8 + (tid >> 6)) * 16) * 256 + lane * 4;
        const unsigned* Gc  = G + (size_t)(lq & 1) * PHG_DW
                                + ((size_t)(d * 64 + b)) * PH_T * 512;
        unsigned* Ho = hout + ((size_t)(lq & 1) * 128 + cid) * PH_T * 128;
        const int hi = tid & 1;
        const float m0 = mrow[(size_t)d * 1024 + tid];
        const float m1 = mrow[(size_t)d * 1024 + 512 + tid];

        // ---- LDS-resident weights: kpc 7..15 (144 KB) ----
#pragma unroll
        for (int k = 0; k < 9; ++k) {
            S.wl[0][k][tid] = *(const uint4*)(w0p + (7 + k) * 256);
            S.wl[1][k][tid] = *(const uint4*)(w1p + (7 + k) * 256);
        }
        __syncthreads();

        for (int t = 0; t < PH_T; ++t) {
            const int cur = t & 1;
            // ---- streamed weights: kpc 0..6, issued first ----
            uint4 s0[7], s1[7];
#pragma unroll
            for (int k = 0; k < 7; ++k) {
                s0[k] = *(const uint4*)(w0p + k * 256);
                s1[k] = *(const uint4*)(w1p + k * 256);
            }
            unsigned g0 = Gc[(size_t)t * 512 +       (tid >> 1)];
            unsigned g1 = Gc[(size_t)t * 512 + 256 + (tid >> 1)];
            const unsigned* hc = S.hbuf[cur];

            int i0 = 0, i1 = 0;
            // LDS-cached chunks (kpc 7..15)
#pragma unroll
            for (int k = 0; k < 9; ++k) {
                uint4 hp = *(const uint4*)&hc[(7 + k) * 4];
                uint4 w0 = S.wl[0][k][tid];
                uint4 w1 = S.wl[1][k][tid];
                i0 = sdot4(w0.x, hp.x, i0); i0 = sdot4(w0.y, hp.y, i0);
                i0 = sdot4(w0.z, hp.z, i0); i0 = sdot4(w0.w, hp.w, i0);
                i1 = sdot4(w1.x, hp.x, i1); i1 = sdot4(w1.y, hp.y, i1);
                i1 = sdot4(w1.z, hp.z, i1); i1 = sdot4(w1.w, hp.w, i1);
            }
            // streamed chunks (kpc 0..6)
#pragma unroll
            for (int k = 0; k < 7; ++k) {
                uint4 hp = *(const uint4*)&hc[k * 4];
                i0 = sdot4(s0[k].x, hp.x, i0); i0 = sdot4(s0[k].y, hp.y, i0);
                i0 = sdot4(s0[k].z, hp.z, i0); i0 = sdot4(s0[k].w, hp.w, i0);
                i1 = sdot4(s1[k].x, hp.x, i1); i1 = sdot4(s1[k].y, hp.y, i1);
                i1 = sdot4(s1[k].z, hp.z, i1); i1 = sdot4(s1[k].w, hp.w, i1);
            }
            float a0 = (float)i0 * m0 + halfsel(g0, hi);
            float a1 = (float)i1 * m1 + halfsel(g1, hi);
            // upper threads publish f (rows 256..511) and o (rows 768..1023)
            if (tid >= 256) {
                S.gsh[tid - 256] = a0;
                S.gsh[tid]       = a1;
            }
            __syncthreads();                 // (1) f/o gates ready

            if (tid < 256) {
                float iv = a0, gg = a1;      // own rows: i (tid), g (512+tid)
                float fv = S.gsh[tid], ov = S.gsh[256 + tid];
                cc = sigf(fv) * cc + sigf(iv) * tanhf(gg);
                hn = sigf(ov) * tanhf(cc);
                int q = (int)rintf(hn * 127.0f);
                unsigned v = ((unsigned)(q & 0xff)) << ((tid & 3) * 8);
                v |= __shfl_xor(v, 1, 64);
                v |= __shfl_xor(v, 2, 64);
                if ((tid & 3) == 0) S.hbuf[cur ^ 1][tid >> 2] = v;
                float hp = __shfl_xor(hn, 1, 64);
                if (!(tid & 1)) Ho[(size_t)t * 128 + (tid >> 1)] = pkh(hn, hp);
            }
            __syncthreads();                 // (2) h(t+1) visible
        }

        if (tid < 256) {
            state[((size_t)cid * 2 + 0) * 256 + tid] = cc;
            state[((size_t)cid * 2 + 1) * 256 + tid] = hn;
        }
    } else if (blockIdx.x < 640) {
        // ================= input GEMM for phase gq (f16, unchanged) ========
        if (gq < 0) return;
        GemmS& S = *(GemmS*)smem;
        int gid = blockIdx.x - 128;                 // 0..511
        int d = gid & 1, rq = (gid >> 1) & 1, tt = (gid >> 2) & 1, b = gid >> 3;
        const float* bv = d ? b_b : b_f;

        int ti = tid >> 4, seg = tid & 15;
        int tg  = gq * PH_T + tt * 32 + ti;
        int tin = d ? (511 - tg) : tg;
        int tok = sent[b * 512 + tin];
        {
            const float4* ep = (const float4*)(emb + (size_t)tok * 256 + seg * 16);
            float4 e0 = ep[0], e1 = ep[1], e2 = ep[2], e3 = ep[3];
            unsigned* xp = &S.x2[ti][seg * 8];
            xp[0] = pkh(e0.x, e0.y); xp[1] = pkh(e0.z, e0.w);
            xp[2] = pkh(e1.x, e1.y); xp[3] = pkh(e1.z, e1.w);
            xp[4] = pkh(e2.x, e2.y); xp[5] = pkh(e2.z, e2.w);
            xp[6] = pkh(e3.x, e3.y); xp[7] = pkh(e3.z, e3.w);
        }
        __syncthreads();

        int row = rq * 512 + tid;
        int blk = row >> 6, lane = tid & 63;
        const unsigned* wp = pk + (((size_t)(2 + d) * 16 + blk) * 32) * 256 + lane * 4;

        float bias = bv[row];
        float acc[32];
#pragma unroll
        for (int t = 0; t < 32; ++t) acc[t] = bias;

        for (int kpc = 0; kpc < 32; ++kpc) {
            uint4 w = *(const uint4*)(wp + kpc * 256);
#pragma unroll
            for (int t = 0; t < 32; ++t) {
                uint4 xv = *(const uint4*)&S.x2[t][kpc * 4];
                acc[t] = dot2u(w.x, xv.x, acc[t]);
                acc[t] = dot2u(w.y, xv.y, acc[t]);
                acc[t] = dot2u(w.z, xv.z, acc[t]);
                acc[t] = dot2u(w.w, xv.w, acc[t]);
            }
        }

        unsigned* Gg = G + (size_t)(gq & 1) * PHG_DW;
        size_t gbase = ((size_t)(d * 64 + b) * PH_T + tt * 32) * 512;
#pragma unroll
        for (int t = 0; t < 32; ++t) {
            float part = __shfl_xor(acc[t], 1, 64);
            if (!(tid & 1))
                Gg[gbase + (size_t)t * 512 + (row >> 1)] = pkh(acc[t], part);
        }
    } else {
        // ================= logit partials for phase logq =================
        if (logq < 0) return;
        LogS& S = *(LogS*)smem;
        int cid = blockIdx.x - 640;                 // 0..127 = (b<<1)|d order? no: cid matches rec cid
        int d = cid & 1, b = cid >> 1;

        for (int i = tid; i < 1280; i += 512) {
            int k = i >> 7, dw = i & 127;
            S.wout2[k][dw] = pkh(W_out[(size_t)k * 512 + d * 256 + 2 * dw],
                                 W_out[(size_t)k * 512 + d * 256 + 2 * dw + 1]);
        }
        __syncthreads();

        int tt = tid >> 3, seg = tid & 7;
        const unsigned* Hp = hout + ((size_t)(logq & 1) * 128 + cid) * PH_T * 128
                                  + (size_t)tt * 128 + seg * 16;
        float acc[10];
#pragma unroll
        for (int k = 0; k < 10; ++k) acc[k] = 0.f;
#pragma unroll
        for (int c4 = 0; c4 < 4; ++c4) {
            uint4 hv = *(const uint4*)(Hp + c4 * 4);
#pragma unroll
            for (int k = 0; k < 10; ++k) {
                const unsigned* wq = &S.wout2[k][seg * 16 + c4 * 4];
                acc[k] = dot2u(hv.x, wq[0], acc[k]);
                acc[k] = dot2u(hv.y, wq[1], acc[k]);
                acc[k] = dot2u(hv.z, wq[2], acc[k]);
                acc[k] = dot2u(hv.w, wq[3], acc[k]);
            }
        }
#pragma unroll
        for (int k = 0; k < 10; ++k) {
            acc[k] += __shfl_xor(acc[k], 1, 64);
            acc[k] += __shfl_xor(acc[k], 2, 64);
            acc[k] += __shfl_xor(acc[k], 4, 64);
        }
        if (seg == 0) {
            int tg = logq * PH_T + tt;
            int t_in = d ? (511 - tg) : tg;
#pragma unroll
            for (int k = 0; k < 10; ++k)
                lh[((size_t)(d * 64 + b) * 512 + t_in) * 10 + k] = acc[k];
        }
    }
}

// ---------------------------------------------------------------------------
// K_V: Viterbi, lane-parallel argmax + register-packed backtrack.
// lanes: j = lane&15 (tag column, j<10 live), ih = lane>>4 (i-subgroup).
// i-groups {0,1,2},{3,4,5},{6,7},{8,9}; 2 shfl_xor combines (ties -> lower i).
// Backtrack: bp packed 10x4bit per t into per-lane u64 regs; shfl chain.
// ---------------------------------------------------------------------------
__global__ __launch_bounds__(64) void viterbi_kernel(
    const float* __restrict__ lh, const float* __restrict__ b_out,
    const float* __restrict__ trans, float* __restrict__ out)
{
    int b = blockIdx.x;
    int l = threadIdx.x;
    __shared__ __align__(16) float ll[512][10];
    __shared__ int   bp[512][10];
    __shared__ float bo[10];
    if (l < 10) { bo[l] = b_out[l]; bp[0][l] = 0; }
    __syncthreads();

    const float* l0 = lh + (size_t)b * 5120;
    const float* l1 = lh + (size_t)(64 + b) * 5120;
    for (int i = l; i < 5120; i += 64) {
        int j = i - (i / 10) * 10;
        ((float*)ll)[i] = l0[i] + l1[i] + bo[j];
    }

    const int j  = l & 15;
    const int ih = l >> 4;
    const int i0tab[4]  = {0, 3, 6, 8};
    const int cnttab[4] = {3, 3, 2, 2};
    const int i0 = i0tab[ih], cnt = cnttab[ih];
    const int jj = (j < 10) ? j : 9;
    float tr0 = trans[(i0 + 0) * 10 + jj];
    float tr1 = trans[(i0 + 1) * 10 + jj];
    float tr2 = trans[((cnt > 2) ? (i0 + 2) : 0) * 10 + jj];
    __syncthreads();

    float v = ll[0][jj];
    for (int t = 1; t < 512; ++t) {
        float p0 = __shfl(v, i0, 64);
        float p1 = __shfl(v, i0 + 1, 64);
        float p2 = __shfl(v, (cnt > 2) ? (i0 + 2) : i0, 64);
        float c0 = p0 + tr0;
        float c1 = p1 + tr1;
        float c2 = (cnt > 2) ? (p2 + tr2) : -3.0e30f;
        float best = c0; int arg = i0;
        if (c1 > best) { best = c1; arg = i0 + 1; }
        if (c2 > best) { best = c2; arg = i0 + 2; }
        float ob = __shfl_xor(best, 16, 64);
        int   oa = __shfl_xor(arg,  16, 64);
        bool tk = (ob > best) || (ob == best && (ih & 1));
        best = tk ? ob : best;  arg = tk ? oa : arg;
        float ob2 = __shfl_xor(best, 32, 64);
        int   oa2 = __shfl_xor(arg,  32, 64);
        bool tk2 = (ob2 > best) || (ob2 == best && ((ih >> 1) & 1));
        best = tk2 ? ob2 : best;  arg = tk2 ? oa2 : arg;
        if (l < 10) bp[t][l] = arg;
        v = ll[t][jj] + best;
    }

    // final score/argmax over lanes 0..9
    float best = -3.0e30f; int arg = 0;
#pragma unroll
    for (int i = 0; i < 10; ++i) {
        float ti = __shfl(v, i, 64);
        bool gt = ti > best;
        best = gt ? ti : best;
        arg  = gt ? i : arg;
    }
    __syncthreads();

    // pack bp rows into per-lane u64 (t = c*64 + l)
    unsigned long long pkr[8];
#pragma unroll
    for (int c = 0; c < 8; ++c) {
        int t = c * 64 + l;
        unsigned long long w = 0;
#pragma unroll
        for (int q = 0; q < 10; ++q)
            w |= ((unsigned long long)(bp[t][q] & 15)) << (4 * q);
        pkr[c] = w;
    }

    // backtrack via shfl (all lanes follow identical tag sequence)
    int preg[8];
#pragma unroll
    for (int c = 0; c < 8; ++c) preg[c] = 0;
    int tag = arg;
    for (int t = 511; t >= 1; --t) {
        if (l == (t & 63)) preg[t >> 6] = tag;
        unsigned long long w = __shfl(pkr[t >> 6], t & 63, 64);
        tag = (int)((w >> (4 * tag)) & 15ull);
    }
    if (l == 0) { preg[0] = tag; out[b] = best; }

    float* po = out + 64 + (size_t)b * 512;
#pragma unroll
    for (int c = 0; c < 8; ++c) po[c * 64 + l] = (float)preg[c];
}

// ---------------------------------------------------------------------------
extern "C" void kernel_launch(void* const* d_in, const int* in_sizes, int n_in,
                              void* d_out, int out_size, void* d_ws, size_t ws_size,
                              hipStream_t stream)
{
    (void)in_sizes; (void)n_in; (void)out_size; (void)ws_size;
    const int*   sent  = (const int*)d_in[0];
    const float* emb   = (const float*)d_in[2];
    const float* Wih_f = (const float*)d_in[3];
    const float* Whh_f = (const float*)d_in[4];
    const float* b_f   = (const float*)d_in[5];
    const float* Wih_b = (const float*)d_in[6];
    const float* Whh_b = (const float*)d_in[7];
    const float* b_b   = (const float*)d_in[8];
    const float* W_out = (const float*)d_in[9];
    const float* b_out = (const float*)d_in[10];
    const float* trans = (const float*)d_in[11];
    float* out = (float*)d_out;

    char* ws = (char*)d_ws;
    unsigned* pk    = (unsigned*)ws;                        // 2 MB
    unsigned* G     = (unsigned*)(ws + 2097152u);           // 33.55 MB
    float*    lh    = (float*)(ws + 35651584u);             // 2.62 MB
    float*    state = (float*)(ws + 38273024u);             // 256 KB
    unsigned* q8    = (unsigned*)(ws + 38535168u);          // 512 KB
    float*    amax  = (float*)(ws + 39059456u);             // 8 KB
    float*    mrowp = (float*)(ws + 39067648u);             // 8 KB
    unsigned* hout  = (unsigned*)(ws + 39075840u);          // 8.39 MB

    hipMemsetAsync(state, 0, (size_t)2 * 64 * 2 * 256 * 4, stream);

    hipLaunchKernelGGL(pack_w, dim3(2048), dim3(256), 0, stream,
                       Whh_f, Whh_b, Wih_f, Wih_b, pk);
    hipLaunchKernelGGL(whh_amax, dim3(512), dim3(256), 0, stream,
                       Whh_f, Whh_b, amax);
    hipLaunchKernelGGL(pack_whh8, dim3(512), dim3(256), 0, stream,
                       Whh_f, Whh_b, amax, q8, mrowp);

    // pipeline: launch running phase q also builds G(q+1) and logits(q-1)
    hipLaunchKernelGGL(fused_phase, dim3(768), dim3(512), 0, stream,
                       pk, q8, mrowp, G, W_out, state, lh, hout,
                       sent, emb, b_f, b_b, -1, 0, -1);
    for (int q = 0; q < NPH; ++q) {
        hipLaunchKernelGGL(fused_phase, dim3(768), dim3(512), 0, stream,
                           pk, q8, mrowp, G, W_out, state, lh, hout,
                           sent, emb, b_f, b_b,
                           q, (q < NPH - 1) ? (q + 1) : -1, q - 1);
    }
    hipLaunchKernelGGL(fused_phase, dim3(768), dim3(512), 0, stream,
                       pk, q8, mrowp, G, W_out, state, lh, hout,
                       sent, emb, b_f, b_b, -1, -1, NPH - 1);

    hipLaunchKernelGGL(viterbi_kernel, dim3(64), dim3(64), 0, stream,
                       lh, b_out, trans, out);
}